// Round 7
// baseline (696.790 us; speedup 1.0000x reference)
//
#include <hip/hip_runtime.h>

#define NN 50000
#define EE 600000
#define ET 650000  // EE + NN self loops
#define NGRAPH 64
#define NCLASS 10
#define NEG 0.2f

typedef unsigned short u16;
typedef __attribute__((ext_vector_type(8))) short short8;
typedef __attribute__((ext_vector_type(4))) float f32x4;

__device__ __forceinline__ float bf2f(u16 u) {
  union { float f; unsigned int i; } v; v.i = ((unsigned int)u) << 16; return v.f;
}
__device__ __forceinline__ u16 f2bf(float f) {
  union { float f; unsigned int i; } v; v.f = f;
  unsigned int r = v.i + 0x7FFFu + ((v.i >> 16) & 1u);
  return (u16)(r >> 16);
}
__device__ __forceinline__ float lrelu(float x) { return x >= 0.f ? x : NEG * x; }
__device__ __forceinline__ float plo(unsigned p) {
  union { float f; unsigned int i; } v; v.i = p << 16; return v.f;
}
__device__ __forceinline__ float phi(unsigned p) {
  union { float f; unsigned int i; } v; v.i = p & 0xffff0000u; return v.f;
}

// ---------------- dtype probe ----------------
__global__ __launch_bounds__(256) void detect_k(const void* __restrict__ x, int* __restrict__ flag) {
  __shared__ int sc[256];
  const float* xf = (const float*)x;
  int t = threadIdx.x, c = 0;
  for (int i = 0; i < 4; ++i) {
    float a = fabsf(xf[t * 4 + i]);
    if (a > 1e-4f && a < 100.f) c++;
  }
  sc[t] = c;
  __syncthreads();
  for (int o = 128; o > 0; o >>= 1) { if (t < o) sc[t] += sc[t + o]; __syncthreads(); }
  if (t == 0) flag[0] = (sc[0] >= 512) ? 1 : 0;
}

__global__ __launch_bounds__(256) void conv_x_k(const void* __restrict__ x, u16* __restrict__ xc,
                                                const int* __restrict__ flag) {
  int i = (blockIdx.x * 256 + threadIdx.x) * 4;
  if (i >= NN * 128) return;
  if (flag[0]) {
    const float* s = (const float*)x + i;
    xc[i] = f2bf(s[0]); xc[i + 1] = f2bf(s[1]); xc[i + 2] = f2bf(s[2]); xc[i + 3] = f2bf(s[3]);
  } else {
    *(uint2*)(xc + i) = *(const uint2*)((const u16*)x + i);
  }
}

// canonicalize W -> bf16, with row-permutation for layers 1,2 (their A input is packed:
// flat u16 index f of a packed row corresponds to channel sigma(f) = (f>>1) + 64*(f&1))
__global__ __launch_bounds__(256) void conv_w_k(const void* __restrict__ w0, const void* __restrict__ w1,
                                                const void* __restrict__ w2, u16* __restrict__ wc,
                                                const int* __restrict__ flag) {
  int idx = blockIdx.x * 256 + threadIdx.x;
  int layer = idx >> 14;
  const void* s = layer == 0 ? w0 : (layer == 1 ? w1 : w2);
  int r = (idx >> 7) & 127, ccol = idx & 127;
  int sr = (layer == 0) ? r : ((r >> 1) + ((r & 1) << 6));
  int l = sr * 128 + ccol;
  wc[idx] = flag[0] ? f2bf(((const float*)s)[l]) : ((const u16*)s)[l];
}

// pf layout: l*384 + {a_src:0, a_dst:128, b:256}; lin_w at 1152 (1280); lin_b at 2432 (10)
__global__ __launch_bounds__(256) void conv_p_k(const void* as0, const void* ad0, const void* b0,
                                                const void* as1, const void* ad1, const void* b1,
                                                const void* as2, const void* ad2, const void* b2,
                                                const void* lw, const void* lb,
                                                float* __restrict__ pf, const int* __restrict__ flag) {
  const void* srcs[11] = {as0, ad0, b0, as1, ad1, b1, as2, ad2, b2, lw, lb};
  const int offs[12] = {0, 128, 256, 384, 512, 640, 768, 896, 1024, 1152, 2432, 2442};
  int f = flag[0];
  for (int idx = threadIdx.x; idx < 2442; idx += 256) {
    int k = 0;
    while (idx >= offs[k + 1]) k++;
    int l = idx - offs[k];
    pf[idx] = f ? ((const float*)srcs[k])[l] : bf2f(((const u16*)srcs[k])[l]);
  }
}

// ---------------- CSR build ----------------
__global__ __launch_bounds__(256) void init_k(int* counts, int* fill, int* roff, float* psum) {
  int i = blockIdx.x * 256 + threadIdx.x;
  if (i < NN) { counts[i] = 1; fill[i] = 0; }
  if (i < NGRAPH * 128) psum[i] = 0.f;
  if (i == 0) roff[NN] = ET;
}

__global__ __launch_bounds__(256) void count_k(const int* __restrict__ ei, int* __restrict__ counts) {
  int e = blockIdx.x * 256 + threadIdx.x;
  if (e < EE) atomicAdd(&counts[ei[EE + e]], 1);
}

__global__ __launch_bounds__(256) void scan_a(const int* __restrict__ counts, int* __restrict__ part) {
  __shared__ int s[256];
  int t = threadIdx.x, i = blockIdx.x * 256 + t;
  s[t] = (i < NN) ? counts[i] : 0;
  __syncthreads();
  for (int o = 128; o > 0; o >>= 1) { if (t < o) s[t] += s[t + o]; __syncthreads(); }
  if (t == 0) part[blockIdx.x] = s[0];
}

__global__ __launch_bounds__(256) void scan_b(int* part) {  // 196 partials
  __shared__ int s[256];
  int t = threadIdx.x;
  int v = (t < 196) ? part[t] : 0;
  s[t] = v;
  __syncthreads();
  for (int o = 1; o < 256; o <<= 1) {
    int add = (t >= o) ? s[t - o] : 0;
    __syncthreads();
    s[t] += add;
    __syncthreads();
  }
  if (t < 196) part[t] = s[t] - v;
}

__global__ __launch_bounds__(256) void scan_c(const int* __restrict__ counts, const int* __restrict__ part,
                                              int* __restrict__ roff) {
  __shared__ int s[256];
  int t = threadIdx.x, i = blockIdx.x * 256 + t;
  int v = (i < NN) ? counts[i] : 0;
  s[t] = v;
  __syncthreads();
  for (int o = 1; o < 256; o <<= 1) {
    int add = (t >= o) ? s[t - o] : 0;
    __syncthreads();
    s[t] += add;
    __syncthreads();
  }
  if (i < NN) roff[i] = part[blockIdx.x] + s[t] - v;
}

__global__ __launch_bounds__(256) void fill_k(const int* __restrict__ ei, const int* __restrict__ roff,
                                              int* __restrict__ fill, int* __restrict__ csr,
                                              int* __restrict__ edst) {
  int i = blockIdx.x * 256 + threadIdx.x;
  if (i >= ET) return;
  int s, d;
  if (i < EE) { s = ei[i]; d = ei[EE + i]; } else { s = d = i - EE; }
  int pos = roff[d] + atomicAdd(&fill[d], 1);
  if ((unsigned)pos < (unsigned)ET) { csr[pos] = s; edst[pos] = d; }
}

// ---------------- GEMM + fused alpha; h2 stored CHUNK-MAJOR: h2[c][node][16 dwords] ----------
__global__ __launch_bounds__(256) void gemm_k(const u16* __restrict__ A, const u16* __restrict__ Wg,
                                              const float* __restrict__ a_src, const float* __restrict__ a_dst,
                                              unsigned* __restrict__ h2, float* __restrict__ al_s,
                                              float* __restrict__ al_d) {
  __shared__ u16 lds[128 * 128];  // W, XOR-swizzled 16B granules
  int tid = threadIdx.x;
  for (int idx = tid; idx < 128 * 128; idx += 256) {
    int k = idx >> 7, c = idx & 127;
    int slot = (k >> 3) ^ (c & 15);
    lds[c * 128 + slot * 8 + (k & 7)] = Wg[idx];
  }
  __syncthreads();
  int wid = tid >> 6, lane = tid & 63;
  int l15 = lane & 15, quad = lane >> 4;
  int row0 = blockIdx.x * 64 + wid * 16;
  f32x4 acc[8];
#pragma unroll
  for (int t = 0; t < 8; ++t) { acc[t][0] = 0.f; acc[t][1] = 0.f; acc[t][2] = 0.f; acc[t][3] = 0.f; }
  int arow = row0 + l15;
  if (arow >= NN) arow = NN - 1;
#pragma unroll
  for (int ks = 0; ks < 4; ++ks) {
    short8 a = *(const short8*)(A + (size_t)arow * 128 + ks * 32 + quad * 8);
#pragma unroll
    for (int t = 0; t < 8; ++t) {
      int col = t * 16 + l15;
      int slot = (ks * 4 + quad) ^ l15;
      short8 b = *(const short8*)(&lds[col * 128 + slot * 8]);
      acc[t] = __builtin_amdgcn_mfma_f32_16x16x32_bf16(a, b, acc[t], 0, 0, 0);
    }
  }
  float vs[8], vd[8];
#pragma unroll
  for (int t = 0; t < 8; ++t) { vs[t] = a_src[t * 16 + l15]; vd[t] = a_dst[t * 16 + l15]; }
#pragma unroll
  for (int r = 0; r < 4; ++r) {
    int row = row0 + quad * 4 + r;
#pragma unroll
    for (int t = 0; t < 4; ++t) {  // chunk t: dwords t*16+l15 -> channels (t*16+l15, +64)
      if (row < NN) {
        unsigned lo = f2bf(acc[t][r]);
        unsigned hiv = f2bf(acc[t + 4][r]);
        h2[(size_t)t * (NN * 16) + (size_t)row * 16 + l15] = lo | (hiv << 16);
      }
    }
    float s0 = 0.f, s1 = 0.f, d0 = 0.f, d1 = 0.f;
#pragma unroll
    for (int t = 0; t < 4; ++t) { s0 += acc[t][r] * vs[t]; d0 += acc[t][r] * vd[t]; }
#pragma unroll
    for (int t = 4; t < 8; ++t) { s1 += acc[t][r] * vs[t]; d1 += acc[t][r] * vd[t]; }
#pragma unroll
    for (int o = 1; o < 16; o <<= 1) {
      s0 += __shfl_xor(s0, o); s1 += __shfl_xor(s1, o);
      d0 += __shfl_xor(d0, o); d1 += __shfl_xor(d1, o);
    }
    if (row < NN && l15 == 0) {
      al_s[2 * row] = s0; al_s[2 * row + 1] = s1;
      al_d[2 * row] = d0; al_d[2 * row + 1] = d1;
    }
  }
}

// ---------------- edge-parallel softmax weights (pure elementwise, no atomics) ----------------
__global__ __launch_bounds__(256) void w_k(const float* __restrict__ al_s, const float* __restrict__ al_d,
                                           const int* __restrict__ csr, const int* __restrict__ edst,
                                           float2* __restrict__ wb) {
  int i = blockIdx.x * 256 + threadIdx.x;
  if (i >= ET) return;
  int s = csr[i], d = edst[i];
  float2 w;
  w.x = __expf(lrelu(al_s[2 * s] + al_d[2 * d]));
  w.y = __expf(lrelu(al_s[2 * s + 1] + al_d[2 * d + 1]));
  wb[i] = w;
}

// ---------------- aggregation: XCD channel-partitioned ----------------
// blockIdx = nb*4 + c; chunk c -> XCDs {c, c+4} (round-robin dispatch): each XCD's L2 only
// sees its own 3.2 MB h2 chunk -> gather re-reads become L2 hits instead of L3/HBM misses.
// wave = 4 nodes x 16 lanes; per edge one 64 B group-gather. den accumulated in-register.
__global__ __launch_bounds__(256) void agg_k(const unsigned* __restrict__ h2, const float2* __restrict__ wb,
                                             const int* __restrict__ roff, const int* __restrict__ csr,
                                             const float* __restrict__ bias, unsigned* __restrict__ oB2,
                                             float* __restrict__ psum, const int* __restrict__ batch,
                                             int last) {
  int c = blockIdx.x & 3, nb = blockIdx.x >> 2;
  int wid = threadIdx.x >> 6, lane = threadIdx.x & 63;
  int li = lane & 15, grp = lane >> 4;
  int n = nb * 16 + wid * 4 + grp;
  bool valid = n < NN;
  if (!valid) n = NN - 1;
  int base = roff[n], deg = roff[n + 1] - base;  // deg >= 1 (self loop)
  int dm = deg;
  dm = max(dm, __shfl_xor(dm, 16));
  dm = max(dm, __shfl_xor(dm, 32));
  const unsigned* hc = h2 + (size_t)c * (NN * 16);
  float acc0 = 0.f, acc1 = 0.f, den0 = 0.f, den1 = 0.f;

  for (int j = 0; j < dm; j += 8) {
    int sv[8]; float wx[8], wy[8]; unsigned p[8];
#pragma unroll
    for (int k = 0; k < 8; ++k) {  // index+weight phase (independent loads)
      int jk = j + k;
      bool ok = jk < deg;
      if (!ok) jk = deg - 1;
      int idx = base + jk;
      sv[k] = csr[idx];
      float2 w = wb[idx];
      wx[k] = ok ? w.x : 0.f;
      wy[k] = ok ? w.y : 0.f;
    }
#pragma unroll
    for (int k = 0; k < 8; ++k) p[k] = hc[(size_t)sv[k] * 16 + li];  // 64 B/group gathers
#pragma unroll
    for (int k = 0; k < 8; ++k) {
      acc0 += wx[k] * plo(p[k]); acc1 += wy[k] * phi(p[k]);
      den0 += wx[k]; den1 += wy[k];
    }
  }

  int ch = c * 16 + li;  // channel-lo; channel-hi = ch + 64
  float v0 = acc0 / (den0 + 1e-16f) + bias[ch];
  float v1 = acc1 / (den1 + 1e-16f) + bias[64 + ch];
  if (last) {
    if (valid) {
      int g = batch[n]; if ((unsigned)g >= (unsigned)NGRAPH) g = 0;
      atomicAdd(&psum[g * 128 + ch], v0);
      atomicAdd(&psum[g * 128 + 64 + ch], v1);
    }
  } else {  // ELU, packed bf16x2 store (row-major packed: next gemm uses permuted W)
    v0 = v0 > 0.f ? v0 : __expf(v0) - 1.f;
    v1 = v1 > 0.f ? v1 : __expf(v1) - 1.f;
    if (valid) {
      unsigned lo = f2bf(v0), hi = f2bf(v1);
      oB2[(size_t)n * 64 + ch] = lo | (hi << 16);
    }
  }
}

// ---------------- final: mean + linear + softmax (f32 output) ----------------
__device__ __forceinline__ int lbound(const int* a, int n, int v) {
  int lo = 0, hi = n;
  while (lo < hi) { int mid = (lo + hi) >> 1; if (a[mid] < v) lo = mid + 1; else hi = mid; }
  return lo;
}

__global__ __launch_bounds__(128) void final_k(const float* __restrict__ psum, const int* __restrict__ batch,
                                               const float* __restrict__ lw, const float* __restrict__ lb,
                                               float* __restrict__ out) {
  __shared__ float p[128];
  __shared__ float lg[NCLASS];
  int g = blockIdx.x, t = threadIdx.x;
  int cnt = lbound(batch, NN, g + 1) - lbound(batch, NN, g);
  p[t] = psum[g * 128 + t] / fmaxf((float)cnt, 1.f);
  __syncthreads();
  if (t < NCLASS) {
    float acc = lb[t];
    for (int c = 0; c < 128; ++c) acc += p[c] * lw[c * NCLASS + t];
    lg[t] = acc;
  }
  __syncthreads();
  if (t < NCLASS) {
    float m = -1e30f;
    for (int j = 0; j < NCLASS; ++j) m = fmaxf(m, lg[j]);
    float sum = 0.f;
    for (int j = 0; j < NCLASS; ++j) sum += __expf(lg[j] - m);
    out[g * NCLASS + t] = __expf(lg[t] - m) / sum;
  }
}

extern "C" void kernel_launch(void* const* d_in, const int* in_sizes, int n_in,
                              void* d_out, int out_size, void* d_ws, size_t ws_size,
                              hipStream_t stream) {
  const void* x = d_in[0];
  const int* ei = (const int*)d_in[1];
  const int* batch = (const int*)d_in[2];
  float* out = (float*)d_out;

  size_t off = 0;
  auto alloc = [&](size_t bytes) -> void* {
    void* p = (char*)d_ws + off;
    off += (bytes + 255) & ~(size_t)255;
    return p;
  };
  int* flag = (int*)alloc(256);
  u16* xc = (u16*)alloc((size_t)NN * 128 * 2);
  u16* wc = (u16*)alloc((size_t)3 * 16384 * 2);
  float* pf = (float*)alloc(2442 * 4);
  unsigned* h2 = (unsigned*)alloc((size_t)NN * 64 * 4);   // chunk-major packed bf16x2
  u16* xb = (u16*)alloc((size_t)NN * 128 * 2);            // row-major packed bf16x2
  float* al_s = (float*)alloc((size_t)NN * 2 * 4);
  float* al_d = (float*)alloc((size_t)NN * 2 * 4);
  int* counts = (int*)alloc((size_t)NN * 4);
  int* fillc = (int*)alloc((size_t)NN * 4);
  int* roff = (int*)alloc((size_t)(NN + 1) * 4);
  int* csr = (int*)alloc((size_t)ET * 4);
  int* edst = (int*)alloc((size_t)ET * 4);
  float2* wb = (float2*)alloc((size_t)ET * 8);
  int* part = (int*)alloc(256 * 4);
  float* psum = (float*)alloc((size_t)NGRAPH * 128 * 4);
  // total ~53 MB

  detect_k<<<1, 256, 0, stream>>>(x, flag);
  conv_x_k<<<6250, 256, 0, stream>>>(x, xc, flag);
  conv_w_k<<<192, 256, 0, stream>>>(d_in[3], d_in[7], d_in[11], wc, flag);
  conv_p_k<<<1, 256, 0, stream>>>(d_in[4], d_in[5], d_in[6], d_in[8], d_in[9], d_in[10],
                                  d_in[12], d_in[13], d_in[14], d_in[15], d_in[16], pf, flag);

  init_k<<<196, 256, 0, stream>>>(counts, fillc, roff, psum);
  count_k<<<2344, 256, 0, stream>>>(ei, counts);
  scan_a<<<196, 256, 0, stream>>>(counts, part);
  scan_b<<<1, 256, 0, stream>>>(part);
  scan_c<<<196, 256, 0, stream>>>(counts, part, roff);
  fill_k<<<2540, 256, 0, stream>>>(ei, roff, fillc, csr, edst);

  const u16* Ain = xc;
  for (int l = 0; l < 3; ++l) {
    gemm_k<<<782, 256, 0, stream>>>(Ain, wc + l * 16384, pf + l * 384, pf + l * 384 + 128,
                                    h2, al_s, al_d);
    w_k<<<2540, 256, 0, stream>>>(al_s, al_d, csr, edst, wb);
    agg_k<<<12500, 256, 0, stream>>>(h2, wb, roff, csr, pf + l * 384 + 256,
                                     (unsigned*)xb, psum, batch, l == 2);
    Ain = xb;
  }
  final_k<<<NGRAPH, 128, 0, stream>>>(psum, batch, pf + 1152, pf + 2432, out);
}

// Round 8
// 525.467 us; speedup vs baseline: 1.3260x; 1.3260x over previous
//
#include <hip/hip_runtime.h>

#define NN 50000
#define EE 600000
#define ET 650000  // EE + NN self loops
#define NGRAPH 64
#define NCLASS 10
#define NEG 0.2f

typedef unsigned short u16;
typedef __attribute__((ext_vector_type(8))) short short8;
typedef __attribute__((ext_vector_type(4))) float f32x4;

__device__ __forceinline__ float bf2f(u16 u) {
  union { float f; unsigned int i; } v; v.i = ((unsigned int)u) << 16; return v.f;
}
__device__ __forceinline__ u16 f2bf(float f) {
  union { float f; unsigned int i; } v; v.f = f;
  unsigned int r = v.i + 0x7FFFu + ((v.i >> 16) & 1u);
  return (u16)(r >> 16);
}
__device__ __forceinline__ float lrelu(float x) { return x >= 0.f ? x : NEG * x; }
__device__ __forceinline__ float plo(unsigned p) {
  union { float f; unsigned int i; } v; v.i = p << 16; return v.f;
}
__device__ __forceinline__ float phi(unsigned p) {
  union { float f; unsigned int i; } v; v.i = p & 0xffff0000u; return v.f;
}

// async global->LDS: each lane 4 B from g+lane, lands at ldsbase+lane*4
__device__ __forceinline__ void gload_lds(const unsigned* g, unsigned* l) {
  __builtin_amdgcn_global_load_lds((const __attribute__((address_space(1))) void*)g,
                                   (__attribute__((address_space(3))) void*)l, 4, 0, 0);
}

// ---------------- dtype probe ----------------
__global__ __launch_bounds__(256) void detect_k(const void* __restrict__ x, int* __restrict__ flag) {
  __shared__ int sc[256];
  const float* xf = (const float*)x;
  int t = threadIdx.x, c = 0;
  for (int i = 0; i < 4; ++i) {
    float a = fabsf(xf[t * 4 + i]);
    if (a > 1e-4f && a < 100.f) c++;
  }
  sc[t] = c;
  __syncthreads();
  for (int o = 128; o > 0; o >>= 1) { if (t < o) sc[t] += sc[t + o]; __syncthreads(); }
  if (t == 0) flag[0] = (sc[0] >= 512) ? 1 : 0;
}

__global__ __launch_bounds__(256) void conv_x_k(const void* __restrict__ x, u16* __restrict__ xc,
                                                const int* __restrict__ flag) {
  int i = (blockIdx.x * 256 + threadIdx.x) * 4;
  if (i >= NN * 128) return;
  if (flag[0]) {
    const float* s = (const float*)x + i;
    xc[i] = f2bf(s[0]); xc[i + 1] = f2bf(s[1]); xc[i + 2] = f2bf(s[2]); xc[i + 3] = f2bf(s[3]);
  } else {
    *(uint2*)(xc + i) = *(const uint2*)((const u16*)x + i);
  }
}

// canonicalize W -> bf16, row-permuted for layers 1,2 (their A input is packed bf16x2:
// flat u16 index f corresponds to channel sigma(f) = (f>>1) + 64*(f&1))
__global__ __launch_bounds__(256) void conv_w_k(const void* __restrict__ w0, const void* __restrict__ w1,
                                                const void* __restrict__ w2, u16* __restrict__ wc,
                                                const int* __restrict__ flag) {
  int idx = blockIdx.x * 256 + threadIdx.x;
  int layer = idx >> 14;
  const void* s = layer == 0 ? w0 : (layer == 1 ? w1 : w2);
  int r = (idx >> 7) & 127, ccol = idx & 127;
  int sr = (layer == 0) ? r : ((r >> 1) + ((r & 1) << 6));
  int l = sr * 128 + ccol;
  wc[idx] = flag[0] ? f2bf(((const float*)s)[l]) : ((const u16*)s)[l];
}

// pf layout: l*384 + {a_src:0, a_dst:128, b:256}; lin_w at 1152 (1280); lin_b at 2432 (10)
__global__ __launch_bounds__(256) void conv_p_k(const void* as0, const void* ad0, const void* b0,
                                                const void* as1, const void* ad1, const void* b1,
                                                const void* as2, const void* ad2, const void* b2,
                                                const void* lw, const void* lb,
                                                float* __restrict__ pf, const int* __restrict__ flag) {
  const void* srcs[11] = {as0, ad0, b0, as1, ad1, b1, as2, ad2, b2, lw, lb};
  const int offs[12] = {0, 128, 256, 384, 512, 640, 768, 896, 1024, 1152, 2432, 2442};
  int f = flag[0];
  for (int idx = threadIdx.x; idx < 2442; idx += 256) {
    int k = 0;
    while (idx >= offs[k + 1]) k++;
    int l = idx - offs[k];
    pf[idx] = f ? ((const float*)srcs[k])[l] : bf2f(((const u16*)srcs[k])[l]);
  }
}

// ---------------- CSR build ----------------
__global__ __launch_bounds__(256) void init_k(int* counts, int* fill, int* roff, float* psum) {
  int i = blockIdx.x * 256 + threadIdx.x;
  if (i < NN) { counts[i] = 1; fill[i] = 0; }
  if (i < NGRAPH * 128) psum[i] = 0.f;
  if (i == 0) roff[NN] = ET;
}

__global__ __launch_bounds__(256) void count_k(const int* __restrict__ ei, int* __restrict__ counts) {
  int e = blockIdx.x * 256 + threadIdx.x;
  if (e < EE) atomicAdd(&counts[ei[EE + e]], 1);
}

__global__ __launch_bounds__(256) void scan_a(const int* __restrict__ counts, int* __restrict__ part) {
  __shared__ int s[256];
  int t = threadIdx.x, i = blockIdx.x * 256 + t;
  s[t] = (i < NN) ? counts[i] : 0;
  __syncthreads();
  for (int o = 128; o > 0; o >>= 1) { if (t < o) s[t] += s[t + o]; __syncthreads(); }
  if (t == 0) part[blockIdx.x] = s[0];
}

__global__ __launch_bounds__(256) void scan_b(int* part) {  // 196 partials
  __shared__ int s[256];
  int t = threadIdx.x;
  int v = (t < 196) ? part[t] : 0;
  s[t] = v;
  __syncthreads();
  for (int o = 1; o < 256; o <<= 1) {
    int add = (t >= o) ? s[t - o] : 0;
    __syncthreads();
    s[t] += add;
    __syncthreads();
  }
  if (t < 196) part[t] = s[t] - v;
}

__global__ __launch_bounds__(256) void scan_c(const int* __restrict__ counts, const int* __restrict__ part,
                                              int* __restrict__ roff) {
  __shared__ int s[256];
  int t = threadIdx.x, i = blockIdx.x * 256 + t;
  int v = (i < NN) ? counts[i] : 0;
  s[t] = v;
  __syncthreads();
  for (int o = 1; o < 256; o <<= 1) {
    int add = (t >= o) ? s[t - o] : 0;
    __syncthreads();
    s[t] += add;
    __syncthreads();
  }
  if (i < NN) roff[i] = part[blockIdx.x] + s[t] - v;
}

__global__ __launch_bounds__(256) void fill_k(const int* __restrict__ ei, const int* __restrict__ roff,
                                              int* __restrict__ fill, int* __restrict__ csr) {
  int i = blockIdx.x * 256 + threadIdx.x;
  if (i >= ET) return;
  int s, d;
  if (i < EE) { s = ei[i]; d = ei[EE + i]; } else { s = d = i - EE; }
  int pos = roff[d] + atomicAdd(&fill[d], 1);
  if ((unsigned)pos < (unsigned)ET) csr[pos] = s;
}

// ---------------- GEMM + fused alpha; h2 ROW-major packed: h2[node][64 dwords] ----------------
__global__ __launch_bounds__(256) void gemm_k(const u16* __restrict__ A, const u16* __restrict__ Wg,
                                              const float* __restrict__ a_src, const float* __restrict__ a_dst,
                                              unsigned* __restrict__ h2, float* __restrict__ al_s,
                                              float* __restrict__ al_d) {
  __shared__ u16 lds[128 * 128];  // W, XOR-swizzled 16B granules
  int tid = threadIdx.x;
  for (int idx = tid; idx < 128 * 128; idx += 256) {
    int k = idx >> 7, c = idx & 127;
    int slot = (k >> 3) ^ (c & 15);
    lds[c * 128 + slot * 8 + (k & 7)] = Wg[idx];
  }
  __syncthreads();
  int wid = tid >> 6, lane = tid & 63;
  int l15 = lane & 15, quad = lane >> 4;
  int row0 = blockIdx.x * 64 + wid * 16;
  f32x4 acc[8];
#pragma unroll
  for (int t = 0; t < 8; ++t) { acc[t][0] = 0.f; acc[t][1] = 0.f; acc[t][2] = 0.f; acc[t][3] = 0.f; }
  int arow = row0 + l15;
  if (arow >= NN) arow = NN - 1;
#pragma unroll
  for (int ks = 0; ks < 4; ++ks) {
    short8 a = *(const short8*)(A + (size_t)arow * 128 + ks * 32 + quad * 8);
#pragma unroll
    for (int t = 0; t < 8; ++t) {
      int col = t * 16 + l15;
      int slot = (ks * 4 + quad) ^ l15;
      short8 b = *(const short8*)(&lds[col * 128 + slot * 8]);
      acc[t] = __builtin_amdgcn_mfma_f32_16x16x32_bf16(a, b, acc[t], 0, 0, 0);
    }
  }
  float vs[8], vd[8];
#pragma unroll
  for (int t = 0; t < 8; ++t) { vs[t] = a_src[t * 16 + l15]; vd[t] = a_dst[t * 16 + l15]; }
#pragma unroll
  for (int r = 0; r < 4; ++r) {
    int row = row0 + quad * 4 + r;
#pragma unroll
    for (int t = 0; t < 4; ++t) {  // dword d = channels (d, d+64)
      if (row < NN) {
        unsigned lo = f2bf(acc[t][r]);
        unsigned hiv = f2bf(acc[t + 4][r]);
        h2[(size_t)row * 64 + t * 16 + l15] = lo | (hiv << 16);
      }
    }
    float s0 = 0.f, s1 = 0.f, d0 = 0.f, d1 = 0.f;
#pragma unroll
    for (int t = 0; t < 4; ++t) { s0 += acc[t][r] * vs[t]; d0 += acc[t][r] * vd[t]; }
#pragma unroll
    for (int t = 4; t < 8; ++t) { s1 += acc[t][r] * vs[t]; d1 += acc[t][r] * vd[t]; }
#pragma unroll
    for (int o = 1; o < 16; o <<= 1) {
      s0 += __shfl_xor(s0, o); s1 += __shfl_xor(s1, o);
      d0 += __shfl_xor(d0, o); d1 += __shfl_xor(d1, o);
    }
    if (row < NN && l15 == 0) {
      al_s[2 * row] = s0; al_s[2 * row + 1] = s1;
      al_d[2 * row] = d0; al_d[2 * row + 1] = d1;
    }
  }
}

// ---------------- aggregation: 1 node/wave, async global_load_lds double-buffered pipeline ----
// Wave-uniform node (readfirstlane) => csr/alpha metadata are scalar (lgkm) loads; the vmcnt
// queue holds ONLY the 16-deep row gathers (1 instr = 256 B row). Wave-private LDS slices,
// no barriers. Weights computed inline (no w_k), denominator accumulated in-register.
#define WAITV(N) asm volatile("s_waitcnt vmcnt(" #N ")" ::: "memory")

__global__ __launch_bounds__(256) void agg_k(const unsigned* __restrict__ h2,
                                             const float* __restrict__ al_s, const float* __restrict__ al_d,
                                             const int* __restrict__ roff, const int* __restrict__ csr,
                                             const float* __restrict__ bias, unsigned* __restrict__ oB2,
                                             float* __restrict__ psum, const int* __restrict__ batch,
                                             int last) {
  __shared__ unsigned sbuf[4][2][16 * 64];  // 4 waves x 2 bufs x 16 rows x 256 B = 32 KB
  int wid = threadIdx.x >> 6, lane = threadIdx.x & 63;
  int n = __builtin_amdgcn_readfirstlane(blockIdx.x * 4 + wid);  // 12500*4 = 50000 exactly
  int base = roff[n], deg = roff[n + 1] - base;  // deg >= 1 (self loop)
  float ad0 = al_d[2 * n], ad1 = al_d[2 * n + 1];
  int nch = (deg + 15) >> 4;
  float acc0 = 0.f, acc1 = 0.f, den0 = 0.f, den1 = 0.f;
  float wAx[16], wAy[16], wBx[16], wBy[16];

#define ISSUE(C, BUF, WX, WY)                                                   \
  do {                                                                          \
    _Pragma("unroll") for (int k = 0; k < 16; ++k) {                            \
      int j = (C) * 16 + k;                                                     \
      int jj = j < deg ? j : deg - 1;                                           \
      int sv = csr[base + jj];                                                  \
      float w0 = 0.f, w1 = 0.f;                                                 \
      if (j < deg) {                                                            \
        w0 = __expf(lrelu(al_s[2 * sv] + ad0));                                 \
        w1 = __expf(lrelu(al_s[2 * sv + 1] + ad1));                             \
      }                                                                         \
      WX[k] = w0; WY[k] = w1; den0 += w0; den1 += w1;                           \
      gload_lds(h2 + (size_t)sv * 64 + lane, &sbuf[wid][BUF][k * 64]);          \
    }                                                                           \
  } while (0)

#define CONSUME(BUF, WX, WY)                                                    \
  do {                                                                          \
    _Pragma("unroll") for (int k = 0; k < 16; ++k) {                            \
      unsigned p = sbuf[wid][BUF][k * 64 + lane];                               \
      acc0 += WX[k] * plo(p); acc1 += WY[k] * phi(p);                           \
    }                                                                           \
  } while (0)

  ISSUE(0, 0, wAx, wAy);
  int c = 0;
  while (1) {
    if (c + 1 < nch) { ISSUE(c + 1, 1, wBx, wBy); WAITV(16); } else { WAITV(0); }
    CONSUME(0, wAx, wAy);
    if (++c >= nch) break;
    if (c + 1 < nch) { ISSUE(c + 1, 0, wAx, wAy); WAITV(16); } else { WAITV(0); }
    CONSUME(1, wBx, wBy);
    if (++c >= nch) break;
  }

  float v0 = acc0 / (den0 + 1e-16f) + bias[lane];
  float v1 = acc1 / (den1 + 1e-16f) + bias[64 + lane];
  if (last) {  // fused mean-pool numerator
    int g = batch[n]; if ((unsigned)g >= (unsigned)NGRAPH) g = 0;
    atomicAdd(&psum[g * 128 + lane], v0);
    atomicAdd(&psum[g * 128 + 64 + lane], v1);
  } else {  // ELU, packed bf16x2 store (next gemm uses row-permuted W)
    v0 = v0 > 0.f ? v0 : __expf(v0) - 1.f;
    v1 = v1 > 0.f ? v1 : __expf(v1) - 1.f;
    unsigned lo = f2bf(v0), hi = f2bf(v1);
    oB2[(size_t)n * 64 + lane] = lo | (hi << 16);
  }
}

// ---------------- final: mean + linear + softmax (f32 output) ----------------
__device__ __forceinline__ int lbound(const int* a, int n, int v) {
  int lo = 0, hi = n;
  while (lo < hi) { int mid = (lo + hi) >> 1; if (a[mid] < v) lo = mid + 1; else hi = mid; }
  return lo;
}

__global__ __launch_bounds__(128) void final_k(const float* __restrict__ psum, const int* __restrict__ batch,
                                               const float* __restrict__ lw, const float* __restrict__ lb,
                                               float* __restrict__ out) {
  __shared__ float p[128];
  __shared__ float lg[NCLASS];
  int g = blockIdx.x, t = threadIdx.x;
  int cnt = lbound(batch, NN, g + 1) - lbound(batch, NN, g);
  p[t] = psum[g * 128 + t] / fmaxf((float)cnt, 1.f);
  __syncthreads();
  if (t < NCLASS) {
    float acc = lb[t];
    for (int c = 0; c < 128; ++c) acc += p[c] * lw[c * NCLASS + t];
    lg[t] = acc;
  }
  __syncthreads();
  if (t < NCLASS) {
    float m = -1e30f;
    for (int j = 0; j < NCLASS; ++j) m = fmaxf(m, lg[j]);
    float sum = 0.f;
    for (int j = 0; j < NCLASS; ++j) sum += __expf(lg[j] - m);
    out[g * NCLASS + t] = __expf(lg[t] - m) / sum;
  }
}

extern "C" void kernel_launch(void* const* d_in, const int* in_sizes, int n_in,
                              void* d_out, int out_size, void* d_ws, size_t ws_size,
                              hipStream_t stream) {
  const void* x = d_in[0];
  const int* ei = (const int*)d_in[1];
  const int* batch = (const int*)d_in[2];
  float* out = (float*)d_out;

  size_t off = 0;
  auto alloc = [&](size_t bytes) -> void* {
    void* p = (char*)d_ws + off;
    off += (bytes + 255) & ~(size_t)255;
    return p;
  };
  int* flag = (int*)alloc(256);
  u16* xc = (u16*)alloc((size_t)NN * 128 * 2);
  u16* wc = (u16*)alloc((size_t)3 * 16384 * 2);
  float* pf = (float*)alloc(2442 * 4);
  unsigned* h2 = (unsigned*)alloc((size_t)NN * 64 * 4);  // row-major packed bf16x2
  u16* xb = (u16*)alloc((size_t)NN * 128 * 2);           // packed bf16x2
  float* al_s = (float*)alloc((size_t)NN * 2 * 4);
  float* al_d = (float*)alloc((size_t)NN * 2 * 4);
  int* counts = (int*)alloc((size_t)NN * 4);
  int* fillc = (int*)alloc((size_t)NN * 4);
  int* roff = (int*)alloc((size_t)(NN + 1) * 4);
  int* csr = (int*)alloc((size_t)ET * 4);
  int* part = (int*)alloc(256 * 4);
  float* psum = (float*)alloc((size_t)NGRAPH * 128 * 4);
  // total ~45 MB

  detect_k<<<1, 256, 0, stream>>>(x, flag);
  conv_x_k<<<6250, 256, 0, stream>>>(x, xc, flag);
  conv_w_k<<<192, 256, 0, stream>>>(d_in[3], d_in[7], d_in[11], wc, flag);
  conv_p_k<<<1, 256, 0, stream>>>(d_in[4], d_in[5], d_in[6], d_in[8], d_in[9], d_in[10],
                                  d_in[12], d_in[13], d_in[14], d_in[15], d_in[16], pf, flag);

  init_k<<<196, 256, 0, stream>>>(counts, fillc, roff, psum);
  count_k<<<2344, 256, 0, stream>>>(ei, counts);
  scan_a<<<196, 256, 0, stream>>>(counts, part);
  scan_b<<<1, 256, 0, stream>>>(part);
  scan_c<<<196, 256, 0, stream>>>(counts, part, roff);
  fill_k<<<2540, 256, 0, stream>>>(ei, roff, fillc, csr);

  const u16* Ain = xc;
  for (int l = 0; l < 3; ++l) {
    gemm_k<<<782, 256, 0, stream>>>(Ain, wc + l * 16384, pf + l * 384, pf + l * 384 + 128,
                                    h2, al_s, al_d);
    agg_k<<<12500, 256, 0, stream>>>(h2, al_s, al_d, roff, csr, pf + l * 384 + 256,
                                     (unsigned*)xb, psum, batch, l == 2);
    Ain = xb;
  }
  final_k<<<NGRAPH, 128, 0, stream>>>(psum, batch, pf + 1152, pf + 2432, out);
}

// Round 9
// 408.060 us; speedup vs baseline: 1.7076x; 1.2877x over previous
//
#include <hip/hip_runtime.h>

#define NN 50000
#define EE 600000
#define ET 650000  // EE + NN self loops
#define NGRAPH 64
#define NCLASS 10
#define NEG 0.2f

typedef unsigned short u16;
typedef __attribute__((ext_vector_type(8))) short short8;
typedef __attribute__((ext_vector_type(4))) float f32x4;

__device__ __forceinline__ float bf2f(u16 u) {
  union { float f; unsigned int i; } v; v.i = ((unsigned int)u) << 16; return v.f;
}
__device__ __forceinline__ u16 f2bf(float f) {
  union { float f; unsigned int i; } v; v.f = f;
  unsigned int r = v.i + 0x7FFFu + ((v.i >> 16) & 1u);
  return (u16)(r >> 16);
}
__device__ __forceinline__ float lrelu(float x) { return x >= 0.f ? x : NEG * x; }
__device__ __forceinline__ float plo(unsigned p) {
  union { float f; unsigned int i; } v; v.i = p << 16; return v.f;
}
__device__ __forceinline__ float phi(unsigned p) {
  union { float f; unsigned int i; } v; v.i = p & 0xffff0000u; return v.f;
}

// ---------------- dtype probe ----------------
__global__ __launch_bounds__(256) void detect_k(const void* __restrict__ x, int* __restrict__ flag) {
  __shared__ int sc[256];
  const float* xf = (const float*)x;
  int t = threadIdx.x, c = 0;
  for (int i = 0; i < 4; ++i) {
    float a = fabsf(xf[t * 4 + i]);
    if (a > 1e-4f && a < 100.f) c++;
  }
  sc[t] = c;
  __syncthreads();
  for (int o = 128; o > 0; o >>= 1) { if (t < o) sc[t] += sc[t + o]; __syncthreads(); }
  if (t == 0) flag[0] = (sc[0] >= 512) ? 1 : 0;
}

__global__ __launch_bounds__(256) void conv_x_k(const void* __restrict__ x, u16* __restrict__ xc,
                                                const int* __restrict__ flag) {
  int i = (blockIdx.x * 256 + threadIdx.x) * 4;
  if (i >= NN * 128) return;
  if (flag[0]) {
    const float* s = (const float*)x + i;
    xc[i] = f2bf(s[0]); xc[i + 1] = f2bf(s[1]); xc[i + 2] = f2bf(s[2]); xc[i + 3] = f2bf(s[3]);
  } else {
    *(uint2*)(xc + i) = *(const uint2*)((const u16*)x + i);
  }
}

// canonicalize W -> bf16, row-permuted for layers 1,2 (their A input is packed bf16x2:
// flat u16 index f corresponds to channel sigma(f) = (f>>1) + 64*(f&1))
__global__ __launch_bounds__(256) void conv_w_k(const void* __restrict__ w0, const void* __restrict__ w1,
                                                const void* __restrict__ w2, u16* __restrict__ wc,
                                                const int* __restrict__ flag) {
  int idx = blockIdx.x * 256 + threadIdx.x;
  int layer = idx >> 14;
  const void* s = layer == 0 ? w0 : (layer == 1 ? w1 : w2);
  int r = (idx >> 7) & 127, ccol = idx & 127;
  int sr = (layer == 0) ? r : ((r >> 1) + ((r & 1) << 6));
  int l = sr * 128 + ccol;
  wc[idx] = flag[0] ? f2bf(((const float*)s)[l]) : ((const u16*)s)[l];
}

// pf layout: l*384 + {a_src:0, a_dst:128, b:256}; lin_w at 1152 (1280); lin_b at 2432 (10)
__global__ __launch_bounds__(256) void conv_p_k(const void* as0, const void* ad0, const void* b0,
                                                const void* as1, const void* ad1, const void* b1,
                                                const void* as2, const void* ad2, const void* b2,
                                                const void* lw, const void* lb,
                                                float* __restrict__ pf, const int* __restrict__ flag) {
  const void* srcs[11] = {as0, ad0, b0, as1, ad1, b1, as2, ad2, b2, lw, lb};
  const int offs[12] = {0, 128, 256, 384, 512, 640, 768, 896, 1024, 1152, 2432, 2442};
  int f = flag[0];
  for (int idx = threadIdx.x; idx < 2442; idx += 256) {
    int k = 0;
    while (idx >= offs[k + 1]) k++;
    int l = idx - offs[k];
    pf[idx] = f ? ((const float*)srcs[k])[l] : bf2f(((const u16*)srcs[k])[l]);
  }
}

// ---------------- CSR build ----------------
__global__ __launch_bounds__(256) void init_k(int* counts, int* fill, int* roff, float* psum) {
  int i = blockIdx.x * 256 + threadIdx.x;
  if (i < NN) { counts[i] = 1; fill[i] = 0; }
  if (i < NGRAPH * 128) psum[i] = 0.f;
  if (i == 0) roff[NN] = ET;
}

__global__ __launch_bounds__(256) void count_k(const int* __restrict__ ei, int* __restrict__ counts) {
  int e = blockIdx.x * 256 + threadIdx.x;
  if (e < EE) atomicAdd(&counts[ei[EE + e]], 1);
}

__global__ __launch_bounds__(256) void scan_a(const int* __restrict__ counts, int* __restrict__ part) {
  __shared__ int s[256];
  int t = threadIdx.x, i = blockIdx.x * 256 + t;
  s[t] = (i < NN) ? counts[i] : 0;
  __syncthreads();
  for (int o = 128; o > 0; o >>= 1) { if (t < o) s[t] += s[t + o]; __syncthreads(); }
  if (t == 0) part[blockIdx.x] = s[0];
}

__global__ __launch_bounds__(256) void scan_b(int* part) {  // 196 partials
  __shared__ int s[256];
  int t = threadIdx.x;
  int v = (t < 196) ? part[t] : 0;
  s[t] = v;
  __syncthreads();
  for (int o = 1; o < 256; o <<= 1) {
    int add = (t >= o) ? s[t - o] : 0;
    __syncthreads();
    s[t] += add;
    __syncthreads();
  }
  if (t < 196) part[t] = s[t] - v;
}

__global__ __launch_bounds__(256) void scan_c(const int* __restrict__ counts, const int* __restrict__ part,
                                              int* __restrict__ roff) {
  __shared__ int s[256];
  int t = threadIdx.x, i = blockIdx.x * 256 + t;
  int v = (i < NN) ? counts[i] : 0;
  s[t] = v;
  __syncthreads();
  for (int o = 1; o < 256; o <<= 1) {
    int add = (t >= o) ? s[t - o] : 0;
    __syncthreads();
    s[t] += add;
    __syncthreads();
  }
  if (i < NN) roff[i] = part[blockIdx.x] + s[t] - v;
}

__global__ __launch_bounds__(256) void fill_k(const int* __restrict__ ei, const int* __restrict__ roff,
                                              int* __restrict__ fill, int* __restrict__ csr) {
  int i = blockIdx.x * 256 + threadIdx.x;
  if (i >= ET) return;
  int s, d;
  if (i < EE) { s = ei[i]; d = ei[EE + i]; } else { s = d = i - EE; }
  int pos = roff[d] + atomicAdd(&fill[d], 1);
  if ((unsigned)pos < (unsigned)ET) csr[pos] = s;
}

// ---------------- GEMM + fused alpha; h2 ROW-major packed: h2[node][64 dwords] ----------------
__global__ __launch_bounds__(256) void gemm_k(const u16* __restrict__ A, const u16* __restrict__ Wg,
                                              const float* __restrict__ a_src, const float* __restrict__ a_dst,
                                              unsigned* __restrict__ h2, float* __restrict__ al_s,
                                              float* __restrict__ al_d) {
  __shared__ u16 lds[128 * 128];  // W, XOR-swizzled 16B granules
  int tid = threadIdx.x;
  for (int idx = tid; idx < 128 * 128; idx += 256) {
    int k = idx >> 7, c = idx & 127;
    int slot = (k >> 3) ^ (c & 15);
    lds[c * 128 + slot * 8 + (k & 7)] = Wg[idx];
  }
  __syncthreads();
  int wid = tid >> 6, lane = tid & 63;
  int l15 = lane & 15, quad = lane >> 4;
  int row0 = blockIdx.x * 64 + wid * 16;
  f32x4 acc[8];
#pragma unroll
  for (int t = 0; t < 8; ++t) { acc[t][0] = 0.f; acc[t][1] = 0.f; acc[t][2] = 0.f; acc[t][3] = 0.f; }
  int arow = row0 + l15;
  if (arow >= NN) arow = NN - 1;
#pragma unroll
  for (int ks = 0; ks < 4; ++ks) {
    short8 a = *(const short8*)(A + (size_t)arow * 128 + ks * 32 + quad * 8);
#pragma unroll
    for (int t = 0; t < 8; ++t) {
      int col = t * 16 + l15;
      int slot = (ks * 4 + quad) ^ l15;
      short8 b = *(const short8*)(&lds[col * 128 + slot * 8]);
      acc[t] = __builtin_amdgcn_mfma_f32_16x16x32_bf16(a, b, acc[t], 0, 0, 0);
    }
  }
  float vs[8], vd[8];
#pragma unroll
  for (int t = 0; t < 8; ++t) { vs[t] = a_src[t * 16 + l15]; vd[t] = a_dst[t * 16 + l15]; }
#pragma unroll
  for (int r = 0; r < 4; ++r) {
    int row = row0 + quad * 4 + r;
#pragma unroll
    for (int t = 0; t < 4; ++t) {  // dword d = channels (d, d+64)
      if (row < NN) {
        unsigned lo = f2bf(acc[t][r]);
        unsigned hiv = f2bf(acc[t + 4][r]);
        h2[(size_t)row * 64 + t * 16 + l15] = lo | (hiv << 16);
      }
    }
    float s0 = 0.f, s1 = 0.f, d0 = 0.f, d1 = 0.f;
#pragma unroll
    for (int t = 0; t < 4; ++t) { s0 += acc[t][r] * vs[t]; d0 += acc[t][r] * vd[t]; }
#pragma unroll
    for (int t = 4; t < 8; ++t) { s1 += acc[t][r] * vs[t]; d1 += acc[t][r] * vd[t]; }
#pragma unroll
    for (int o = 1; o < 16; o <<= 1) {
      s0 += __shfl_xor(s0, o); s1 += __shfl_xor(s1, o);
      d0 += __shfl_xor(d0, o); d1 += __shfl_xor(d1, o);
    }
    if (row < NN && l15 == 0) {
      al_s[2 * row] = s0; al_s[2 * row + 1] = s1;
      al_d[2 * row] = d0; al_d[2 * row + 1] = d1;
    }
  }
}

// ---------------- segment softmax + aggregation (R4 structure: one wave per dst node) ---------
__global__ __launch_bounds__(256) void agg_k(const unsigned* __restrict__ h2, const float* __restrict__ al_s,
                                             const float* __restrict__ al_d, const int* __restrict__ roff,
                                             const int* __restrict__ csr, const float* __restrict__ bias,
                                             unsigned* __restrict__ oB2, float* __restrict__ psum,
                                             const int* __restrict__ batch, int last) {
  int wid = threadIdx.x >> 6, lane = threadIdx.x & 63;
  int n = blockIdx.x * 4 + wid;  // 12500*4 = 50000 exactly
  int base = roff[n], deg = roff[n + 1] - base;
  float ad0 = al_d[2 * n], ad1 = al_d[2 * n + 1];
  float acc0 = 0.f, acc1 = 0.f, den0, den1;

  if (deg <= 64) {  // fast path (covers ~all nodes at mean deg 13)
    int sv = 0;
    float e0 = -1e30f, e1 = -1e30f;
    if (lane < deg) {
      sv = csr[base + lane];
      e0 = lrelu(al_s[2 * sv] + ad0);
      e1 = lrelu(al_s[2 * sv + 1] + ad1);
    }
    float m0 = e0, m1 = e1;
#pragma unroll
    for (int o = 32; o > 0; o >>= 1) { m0 = fmaxf(m0, __shfl_xor(m0, o)); m1 = fmaxf(m1, __shfl_xor(m1, o)); }
    float w0 = (lane < deg) ? __expf(e0 - m0) : 0.f;
    float w1 = (lane < deg) ? __expf(e1 - m1) : 0.f;
    den0 = w0; den1 = w1;
#pragma unroll
    for (int o = 32; o > 0; o >>= 1) { den0 += __shfl_xor(den0, o); den1 += __shfl_xor(den1, o); }
    int j = 0;
    for (; j + 8 <= deg; j += 8) {  // 8 independent gathers in flight
      int s0 = __shfl(sv, j), s1 = __shfl(sv, j + 1), s2 = __shfl(sv, j + 2), s3 = __shfl(sv, j + 3);
      int s4 = __shfl(sv, j + 4), s5 = __shfl(sv, j + 5), s6 = __shfl(sv, j + 6), s7 = __shfl(sv, j + 7);
      unsigned p0 = h2[(size_t)s0 * 64 + lane];
      unsigned p1 = h2[(size_t)s1 * 64 + lane];
      unsigned p2 = h2[(size_t)s2 * 64 + lane];
      unsigned p3 = h2[(size_t)s3 * 64 + lane];
      unsigned p4 = h2[(size_t)s4 * 64 + lane];
      unsigned p5 = h2[(size_t)s5 * 64 + lane];
      unsigned p6 = h2[(size_t)s6 * 64 + lane];
      unsigned p7 = h2[(size_t)s7 * 64 + lane];
      float a0 = __shfl(w0, j), a1 = __shfl(w0, j + 1), a2 = __shfl(w0, j + 2), a3 = __shfl(w0, j + 3);
      float a4 = __shfl(w0, j + 4), a5 = __shfl(w0, j + 5), a6 = __shfl(w0, j + 6), a7 = __shfl(w0, j + 7);
      float b0 = __shfl(w1, j), b1 = __shfl(w1, j + 1), b2 = __shfl(w1, j + 2), b3 = __shfl(w1, j + 3);
      float b4 = __shfl(w1, j + 4), b5 = __shfl(w1, j + 5), b6 = __shfl(w1, j + 6), b7 = __shfl(w1, j + 7);
      acc0 += a0 * plo(p0); acc1 += b0 * phi(p0);
      acc0 += a1 * plo(p1); acc1 += b1 * phi(p1);
      acc0 += a2 * plo(p2); acc1 += b2 * phi(p2);
      acc0 += a3 * plo(p3); acc1 += b3 * phi(p3);
      acc0 += a4 * plo(p4); acc1 += b4 * phi(p4);
      acc0 += a5 * plo(p5); acc1 += b5 * phi(p5);
      acc0 += a6 * plo(p6); acc1 += b6 * phi(p6);
      acc0 += a7 * plo(p7); acc1 += b7 * phi(p7);
    }
    for (; j < deg; ++j) {
      int sj = __shfl(sv, j);
      unsigned p = h2[(size_t)sj * 64 + lane];
      acc0 += __shfl(w0, j) * plo(p);
      acc1 += __shfl(w1, j) * phi(p);
    }
  } else {  // generic chunked path (rare at mean deg 13)
    float m0 = -1e30f, m1 = -1e30f;
    for (int i = lane; i < deg; i += 64) {
      int s = csr[base + i];
      m0 = fmaxf(m0, lrelu(al_s[2 * s] + ad0));
      m1 = fmaxf(m1, lrelu(al_s[2 * s + 1] + ad1));
    }
#pragma unroll
    for (int o = 32; o > 0; o >>= 1) { m0 = fmaxf(m0, __shfl_xor(m0, o)); m1 = fmaxf(m1, __shfl_xor(m1, o)); }
    den0 = 0.f; den1 = 0.f;
    for (int c0 = 0; c0 < deg; c0 += 64) {
      int cnt = min(64, deg - c0);
      int sv = 0; float w0 = 0.f, w1 = 0.f;
      if (lane < cnt) {
        sv = csr[base + c0 + lane];
        w0 = __expf(lrelu(al_s[2 * sv] + ad0) - m0);
        w1 = __expf(lrelu(al_s[2 * sv + 1] + ad1) - m1);
      }
      for (int j = 0; j < cnt; ++j) {
        int sj = __shfl(sv, j);
        unsigned p = h2[(size_t)sj * 64 + lane];
        float w0j = __shfl(w0, j), w1j = __shfl(w1, j);
        acc0 += w0j * plo(p); acc1 += w1j * phi(p);
        den0 += w0j; den1 += w1j;
      }
    }
  }

  float v0 = acc0 / (den0 + 1e-16f) + bias[lane];
  float v1 = acc1 / (den1 + 1e-16f) + bias[64 + lane];
  if (last) {  // fused mean-pool numerator
    int g = batch[n]; if ((unsigned)g >= (unsigned)NGRAPH) g = 0;
    atomicAdd(&psum[g * 128 + lane], v0);
    atomicAdd(&psum[g * 128 + 64 + lane], v1);
  } else {  // ELU, packed bf16x2 store (next gemm uses row-permuted W)
    v0 = v0 > 0.f ? v0 : __expf(v0) - 1.f;
    v1 = v1 > 0.f ? v1 : __expf(v1) - 1.f;
    unsigned lo = f2bf(v0), hi = f2bf(v1);
    oB2[(size_t)n * 64 + lane] = lo | (hi << 16);
  }
}

// ---------------- final: mean + linear + softmax (f32 output) ----------------
__device__ __forceinline__ int lbound(const int* a, int n, int v) {
  int lo = 0, hi = n;
  while (lo < hi) { int mid = (lo + hi) >> 1; if (a[mid] < v) lo = mid + 1; else hi = mid; }
  return lo;
}

__global__ __launch_bounds__(128) void final_k(const float* __restrict__ psum, const int* __restrict__ batch,
                                               const float* __restrict__ lw, const float* __restrict__ lb,
                                               float* __restrict__ out) {
  __shared__ float p[128];
  __shared__ float lg[NCLASS];
  int g = blockIdx.x, t = threadIdx.x;
  int cnt = lbound(batch, NN, g + 1) - lbound(batch, NN, g);
  p[t] = psum[g * 128 + t] / fmaxf((float)cnt, 1.f);
  __syncthreads();
  if (t < NCLASS) {
    float acc = lb[t];
    for (int c = 0; c < 128; ++c) acc += p[c] * lw[c * NCLASS + t];
    lg[t] = acc;
  }
  __syncthreads();
  if (t < NCLASS) {
    float m = -1e30f;
    for (int j = 0; j < NCLASS; ++j) m = fmaxf(m, lg[j]);
    float sum = 0.f;
    for (int j = 0; j < NCLASS; ++j) sum += __expf(lg[j] - m);
    out[g * NCLASS + t] = __expf(lg[t] - m) / sum;
  }
}

extern "C" void kernel_launch(void* const* d_in, const int* in_sizes, int n_in,
                              void* d_out, int out_size, void* d_ws, size_t ws_size,
                              hipStream_t stream) {
  const void* x = d_in[0];
  const int* ei = (const int*)d_in[1];
  const int* batch = (const int*)d_in[2];
  float* out = (float*)d_out;

  size_t off = 0;
  auto alloc = [&](size_t bytes) -> void* {
    void* p = (char*)d_ws + off;
    off += (bytes + 255) & ~(size_t)255;
    return p;
  };
  int* flag = (int*)alloc(256);
  u16* xc = (u16*)alloc((size_t)NN * 128 * 2);
  u16* wc = (u16*)alloc((size_t)3 * 16384 * 2);
  float* pf = (float*)alloc(2442 * 4);
  unsigned* h2 = (unsigned*)alloc((size_t)NN * 64 * 4);  // row-major packed bf16x2
  unsigned* xb = (unsigned*)alloc((size_t)NN * 64 * 4);  // packed bf16x2
  float* al_s = (float*)alloc((size_t)NN * 2 * 4);
  float* al_d = (float*)alloc((size_t)NN * 2 * 4);
  int* counts = (int*)alloc((size_t)NN * 4);
  int* fillc = (int*)alloc((size_t)NN * 4);
  int* roff = (int*)alloc((size_t)(NN + 1) * 4);
  int* csr = (int*)alloc((size_t)ET * 4);
  int* part = (int*)alloc(256 * 4);
  float* psum = (float*)alloc((size_t)NGRAPH * 128 * 4);
  // total ~45 MB

  detect_k<<<1, 256, 0, stream>>>(x, flag);
  conv_x_k<<<6250, 256, 0, stream>>>(x, xc, flag);
  conv_w_k<<<192, 256, 0, stream>>>(d_in[3], d_in[7], d_in[11], wc, flag);
  conv_p_k<<<1, 256, 0, stream>>>(d_in[4], d_in[5], d_in[6], d_in[8], d_in[9], d_in[10],
                                  d_in[12], d_in[13], d_in[14], d_in[15], d_in[16], pf, flag);

  init_k<<<196, 256, 0, stream>>>(counts, fillc, roff, psum);
  count_k<<<2344, 256, 0, stream>>>(ei, counts);
  scan_a<<<196, 256, 0, stream>>>(counts, part);
  scan_b<<<1, 256, 0, stream>>>(part);
  scan_c<<<196, 256, 0, stream>>>(counts, part, roff);
  fill_k<<<2540, 256, 0, stream>>>(ei, roff, fillc, csr);

  const u16* Ain = xc;
  for (int l = 0; l < 3; ++l) {
    gemm_k<<<782, 256, 0, stream>>>(Ain, wc + l * 16384, pf + l * 384, pf + l * 384 + 128,
                                    h2, al_s, al_d);
    agg_k<<<12500, 256, 0, stream>>>(h2, al_s, al_d, roff, csr, pf + l * 384 + 256,
                                     xb, psum, batch, l == 2);
    Ain = (const u16*)xb;
  }
  final_k<<<NGRAPH, 128, 0, stream>>>(psum, batch, pf + 1152, pf + 2432, out);
}